// Round 12
// baseline (197.452 us; speedup 1.0000x reference)
//
#include <hip/hip_runtime.h>
#include <hip/hip_bf16.h>
#include <stdint.h>

// Problem constants
constexpr int S_ = 2048, H_ = 32, G_ = 8, HPG_ = 4, D_ = 128, MODEL_ = 4096;

typedef __attribute__((ext_vector_type(4))) float f32x4;
typedef __attribute__((ext_vector_type(8))) short bf16x8;
typedef __attribute__((ext_vector_type(4))) short bf16x4;

__device__ inline unsigned short f2bf(float f) {
  unsigned u = __float_as_uint(f);
  u += 0x7FFFu + ((u >> 16) & 1u);   // round-to-nearest-even
  return (unsigned short)(u >> 16);
}

__device__ inline unsigned cvt_pk_bf16(float lo, float hi) {
  unsigned r;
  asm("v_cvt_pk_bf16_f32 %0, %1, %2" : "=v"(r) : "v"(lo), "v"(hi));
  return r;
}

__device__ inline void gload_lds16(const void* g, void* l) {
  __builtin_amdgcn_global_load_lds(
      (const __attribute__((address_space(1))) unsigned int*)g,
      (__attribute__((address_space(3))) unsigned int*)l,
      16, 0, 0);
}

// ---------------- w_out f32 -> bf16 (runs AFTER attn; aliases k/v region) ---
__global__ __launch_bounds__(256) void cvt_f32_to_bf16(
    const float* __restrict__ in, unsigned short* __restrict__ out, int n4) {
  int i = blockIdx.x * 256 + threadIdx.x;
  if (i < n4) {
    float4 v = reinterpret_cast<const float4*>(in)[i];
    bf16x4 o;
    o[0] = f2bf(v.x); o[1] = f2bf(v.y); o[2] = f2bf(v.z); o[3] = f2bf(v.w);
    reinterpret_cast<bf16x4*>(out)[i] = o;
  }
}

// ---------------- K: [S][G][D] f32 -> [G][S][D] bf16 ----------------
__global__ __launch_bounds__(256) void cvt_k_kernel(
    const float* __restrict__ in, unsigned short* __restrict__ out) {
  int i = blockIdx.x * 256 + threadIdx.x;   // over S*G*D/4
  int d4 = i & 31, g = (i >> 5) & 7, s = i >> 8;
  float4 v = reinterpret_cast<const float4*>(in)[i];
  bf16x4 o;
  o[0] = f2bf(v.x); o[1] = f2bf(v.y); o[2] = f2bf(v.z); o[3] = f2bf(v.w);
  reinterpret_cast<bf16x4*>(out)[(g * S_ + s) * 32 + d4] = o;
}

// ---------------- V: [S][G][D] f32 -> [G][D][S] bf16 (transpose) -----------
__global__ __launch_bounds__(256) void cvt_v_kernel(
    const float* __restrict__ in, unsigned short* __restrict__ out) {
  __shared__ float t[64][33];
  int s0 = blockIdx.x * 64, d0 = blockIdx.y * 32, g = blockIdx.z;
  int tid = threadIdx.x;
#pragma unroll
  for (int p = 0; p < 2; ++p) {
    int idx = p * 256 + tid;
    int s = idx >> 3, dq = (idx & 7) * 4;
    float4 v = *reinterpret_cast<const float4*>(
        in + ((size_t)(s0 + s) * G_ + g) * D_ + d0 + dq);
    t[s][dq] = v.x; t[s][dq + 1] = v.y; t[s][dq + 2] = v.z; t[s][dq + 3] = v.w;
  }
  __syncthreads();
  int d = tid >> 3, sq = (tid & 7) * 8;
  bf16x8 o;
#pragma unroll
  for (int j = 0; j < 8; ++j) o[j] = f2bf(t[sq + j][d]);
  *reinterpret_cast<bf16x8*>(out + ((size_t)g * D_ + d0 + d) * S_ + s0 + sq) = o;
}

// ---------------- flash attention, 16x16 MFMA, 8 waves, 16 q/wave ----------------
// grid (S/128, H), 512 threads = 8 waves; wave w owns q rows qt*128+w*16+(l&15).
// 4096 waves total = 4 waves/SIMD (vs 2 for 32q designs) -- the TLP fix.
// QK^T: S^T = K·Q^T with sigma-PERMUTED A rows: acc_A row a <- K[8(a>>2)+(a&3)],
// acc_B <- +4. Then lane-group g holds P[kv=8g..8g+7] == PV B-frag order:
// P->pf is 4 cvt_pk, ZERO cross-lane. Softmax reduce = shfl_xor 16,32.
// PV: O^T[d][q] += Vt·P^T, one 16x16x32 MFMA per 16-d block (8 total).
// K tile [32 kv][128 d] swizzle (kv&15)<<4; V tile [128 d][32 kv] row-major,
// swizzle on 256B super-rows (R=d>>2): ((R&7)<<4). Both ~2-way reads (free).
// R4 cadence: 3 buffers, counted vmcnt(2), one barrier/tile.
constexpr int QB2 = 128, KVB = 32, NT = S_ / KVB;   // 64 tiles
constexpr float RTHR = 8.0f;   // defer-max threshold, log2 units (P <= 256)

__global__ __launch_bounds__(512, 2) void attn16_kernel(
    const float* __restrict__ q, const unsigned short* __restrict__ kb,
    const unsigned short* __restrict__ vtb, unsigned short* __restrict__ aout) {
  // 3 buffers x (K 8KB + V 8KB) = 48KB; epilogue Ol (32KB) reuses [0,32KB).
  __shared__ __align__(16) char smem[49152];

  const int qt = blockIdx.x, h = blockIdx.y;
  const int g = h >> 2;   // HPG = 4
  const int tid = threadIdx.x, w = tid >> 6, lane = tid & 63;
  const int a = lane & 15, gr = lane >> 4;       // a = q-col / A-row, gr = k-group
  const int kvA = 8 * (a >> 2) + (a & 3);        // sigma_A(a)
  const int kvB = kvA + 4;                       // sigma_B(a)

  // ---- Q B-frags (scale*log2e folded): qf[c] holds Q[q][c*32+gr*8+e] ----
  const float scale2 = 0.12751742354783493f;  // (1/sqrt(128)) * log2(e)
  bf16x8 qf[4];
  {
    const int qrow = qt * QB2 + w * 16 + a;
    const float* qp = q + ((size_t)qrow * H_ + h) * D_ + gr * 8;
#pragma unroll
    for (int c = 0; c < 4; ++c) {
      float4 x = *(const float4*)(qp + c * 32);
      float4 y = *(const float4*)(qp + c * 32 + 4);
      bf16x8 f;
      f[0] = f2bf(x.x * scale2); f[1] = f2bf(x.y * scale2);
      f[2] = f2bf(x.z * scale2); f[3] = f2bf(x.w * scale2);
      f[4] = f2bf(y.x * scale2); f[5] = f2bf(y.y * scale2);
      f[6] = f2bf(y.z * scale2); f[7] = f2bf(y.w * scale2);
      qf[c] = f;
    }
  }

  // ---- staging sources (pre-swizzled; linear LDS dest; 1 K + 1 V slice/thread)
  // K: phys p -> kv = p>>8, log col byte = (p&255) ^ ((kv&15)<<4)
  // V: phys p -> R = p>>8, il = (p&255) ^ ((R&7)<<4), d = R*4+(il>>6), kv=(il&63)>>1
  const unsigned short* pK;
  const unsigned short* pV;
  {
    const unsigned short* kg = kb + (size_t)g * S_ * D_;
    const unsigned short* vg = vtb + (size_t)g * D_ * S_;
    int p = tid * 16;
    int kvr = p >> 8;
    pK = kg + (size_t)kvr * D_ + (((p & 255) ^ ((kvr & 15) << 4)) >> 1);
    int R = p >> 8;
    int il = (p & 255) ^ ((R & 7) << 4);
    pV = vg + (size_t)(R * 4 + (il >> 6)) * S_ + ((il & 63) >> 1);
  }

  auto stage = [&](int t) {
    char* base = smem + (t % 3) * 16384;
    gload_lds16(pK + (size_t)(t * KVB) * D_, base + tid * 16);
    gload_lds16(pV + t * KVB, base + 8192 + tid * 16);
  };

  f32x4 of[8];
#pragma unroll
  for (int i = 0; i < 8; ++i) of[i] = (f32x4)0.f;
  float m = -1e30f, l = 0.f;

  // per-lane precomputed LDS addressing
  const unsigned swzA = (unsigned)(kvA & 15) << 4, baseA = (unsigned)kvA * 256;
  const unsigned swzB = (unsigned)(kvB & 15) << 4, baseB = (unsigned)kvB * 256;
  const int a2 = a >> 2, a3 = a & 3;
  // V: d = db*16+a -> R = db*4+a2; swz = ((db&1)*4 + a2)<<4; o = a3*64+16*gr
  const unsigned vO = (unsigned)(a3 * 64 + 16 * gr);
  const unsigned vSwzE = (unsigned)a2 << 4;            // db even
  const unsigned vSwzO = (unsigned)(4 + a2) << 4;      // db odd

  // ---- prologue: two tiles in flight ----
  stage(0);
  stage(1);

  for (int t = 0; t < NT; ++t) {
    if (t + 1 < NT) asm volatile("s_waitcnt vmcnt(2)" ::: "memory");
    else            asm volatile("s_waitcnt vmcnt(0)" ::: "memory");
    __builtin_amdgcn_s_barrier();
    if (t + 2 < NT) stage(t + 2);

    const char* Kd = smem + (t % 3) * 16384;
    const char* Vd = Kd + 8192;

    // ---- QK^T: two independent 4-deep chains (acc_A kv=8g+r, acc_B +4) ----
    f32x4 sA = (f32x4)0.f, sB = (f32x4)0.f;
    __builtin_amdgcn_s_setprio(1);
#pragma unroll
    for (int c = 0; c < 4; ++c) {
      unsigned o = (unsigned)(64 * c + 16 * gr);
      bf16x8 kfA = *(const bf16x8*)(Kd + baseA + (o ^ swzA));
      bf16x8 kfB = *(const bf16x8*)(Kd + baseB + (o ^ swzB));
      sA = __builtin_amdgcn_mfma_f32_16x16x32_bf16(kfA, qf[c], sA, 0, 0, 0);
      sB = __builtin_amdgcn_mfma_f32_16x16x32_bf16(kfB, qf[c], sB, 0, 0, 0);
    }
    __builtin_amdgcn_s_setprio(0);
    // lane holds S[kv = 8*gr + r][q=a] (sA r=0..3) and S[8*gr+4+r][q] (sB)

    // ---- online softmax (exp2 domain) ----
    float tmax = fmaxf(fmaxf(fmaxf(sA[0], sA[1]), fmaxf(sA[2], sA[3])),
                       fmaxf(fmaxf(sB[0], sB[1]), fmaxf(sB[2], sB[3])));
    tmax = fmaxf(tmax, __shfl_xor(tmax, 16));
    tmax = fmaxf(tmax, __shfl_xor(tmax, 32));
    if (__any(tmax > m + RTHR)) {
      float mnew = fmaxf(m, tmax);
      float alpha = __builtin_exp2f(m - mnew);
#pragma unroll
      for (int i = 0; i < 8; ++i)
#pragma unroll
        for (int r = 0; r < 4; ++r) of[i][r] *= alpha;
      l *= alpha;
      m = mnew;
    }
    float pA0 = __builtin_exp2f(sA[0] - m), pA1 = __builtin_exp2f(sA[1] - m);
    float pA2 = __builtin_exp2f(sA[2] - m), pA3 = __builtin_exp2f(sA[3] - m);
    float pB0 = __builtin_exp2f(sB[0] - m), pB1 = __builtin_exp2f(sB[1] - m);
    float pB2 = __builtin_exp2f(sB[2] - m), pB3 = __builtin_exp2f(sB[3] - m);
    float sum = ((pA0 + pA1) + (pA2 + pA3)) + ((pB0 + pB1) + (pB2 + pB3));
    sum += __shfl_xor(sum, 16);
    sum += __shfl_xor(sum, 32);
    l += sum;

    // ---- P -> PV B-frag: lane-local, zero shuffle (sigma did the work) ----
    unsigned fr[4] = {cvt_pk_bf16(pA0, pA1), cvt_pk_bf16(pA2, pA3),
                      cvt_pk_bf16(pB0, pB1), cvt_pk_bf16(pB2, pB3)};
    bf16x8 pf;
    __builtin_memcpy(&pf, fr, 16);

    // ---- PV: of[db] += Vt(16d x 32kv) · P^T, 8 independent MFMAs ----
    __builtin_amdgcn_s_setprio(1);
#pragma unroll
    for (int db = 0; db < 8; ++db) {
      unsigned base = (unsigned)((db * 4 + a2) * 256);
      unsigned o = vO ^ ((db & 1) ? vSwzO : vSwzE);
      bf16x8 vf = *(const bf16x8*)(Vd + base + o);
      of[db] = __builtin_amdgcn_mfma_f32_16x16x32_bf16(vf, pf, of[db], 0, 0, 0);
    }
    __builtin_amdgcn_s_setprio(0);
  }

  // ---- epilogue: normalize, transpose via LDS, coalesced bf16 store ----
  __syncthreads();   // all waves past final barrier before Ol overwrites bufs
  float inv = 1.0f / l;
  unsigned short* Ol = (unsigned short*)smem;   // [128 q][128 d] bf16 = 32KB
  const int ql = w * 16 + a;
  const unsigned swzq = (unsigned)(ql & 7) << 4;
#pragma unroll
  for (int db = 0; db < 8; ++db) {
    int d0 = db * 16 + 4 * gr;                  // of[db] regs r -> d = d0 + r
    unsigned pk0 = cvt_pk_bf16(of[db][0] * inv, of[db][1] * inv);
    unsigned pk1 = cvt_pk_bf16(of[db][2] * inv, of[db][3] * inv);
    *(unsigned*)((char*)Ol + (((unsigned)(ql * 256 + d0 * 2)) ^ swzq)) = pk0;
    *(unsigned*)((char*)Ol + (((unsigned)(ql * 256 + (d0 + 2) * 2)) ^ swzq)) = pk1;
  }
  __syncthreads();
  const size_t obase = ((size_t)qt * QB2) * MODEL_ + (size_t)h * D_;
#pragma unroll
  for (int pass = 0; pass < 4; ++pass) {
    int row = pass * 32 + (tid >> 4);
    int c = tid & 15;
    unsigned off = ((unsigned)(row * 256 + c * 16)) ^ ((unsigned)(row & 7) << 4);
    bf16x8 vv = *(const bf16x8*)((char*)Ol + off);
    *(bf16x8*)(aout + obase + (size_t)row * MODEL_ + c * 8) = vv;
  }
}

// ---------------- out-projection GEMM: C = A @ B^T + bias (m97 structure) ----
// T1 XCD swizzle: 1D grid of 512; lin = (id%8)*64 + id/8; column-major panels.
constexpr int BM = 128, BN = 128, BK = 64;

__global__ __launch_bounds__(256, 2) void gemm_bt_bias(
    const unsigned short* __restrict__ A, const unsigned short* __restrict__ B,
    const float* __restrict__ bias, float* __restrict__ C) {
  __shared__ unsigned short As[BM * BK];
  __shared__ unsigned short Bs[BN * BK];

  const int tid = threadIdx.x;
  const int w = tid >> 6, lane = tid & 63;
  const int wr = w >> 1, wc = w & 1;
  const int r16 = lane & 15, g4 = lane >> 4;
  const int id = blockIdx.x;
  const int lin = (id & 7) * 64 + (id >> 3);
  const int row0 = (lin & 15) * BM, col0 = (lin >> 4) * BN;

  f32x4 acc[4][4];
#pragma unroll
  for (int m = 0; m < 4; ++m)
#pragma unroll
    for (int n = 0; n < 4; ++n) acc[m][n] = (f32x4)0.f;

  for (int kt = 0; kt < MODEL_ / BK; ++kt) {
    const int k0 = kt * BK;
    __syncthreads();
#pragma unroll
    for (int j = 0; j < 4; ++j) {
      int chunk = w * 4 + j;
      int sb = chunk * 1024 + lane * 16;
      int srow = sb >> 7;
      int lb = sb ^ ((srow & 7) << 4);
      int kk = (lb & 127) >> 1;
      gload_lds16(A + (size_t)(row0 + srow) * MODEL_ + k0 + kk,
                  (char*)As + chunk * 1024);
      gload_lds16(B + (size_t)(col0 + srow) * MODEL_ + k0 + kk,
                  (char*)Bs + chunk * 1024);
    }
    asm volatile("s_waitcnt vmcnt(0)" ::: "memory");
    __syncthreads();

#pragma unroll
    for (int kc = 0; kc < 2; ++kc) {
      bf16x8 af[4], bfr[4];
#pragma unroll
      for (int m = 0; m < 4; ++m) {
        int row = wr * 64 + m * 16 + r16;
        unsigned off = ((unsigned)(row * 128 + (kc * 32 + g4 * 8) * 2)) ^ ((row & 7) << 4);
        af[m] = *(bf16x8*)((char*)As + off);
      }
#pragma unroll
      for (int n = 0; n < 4; ++n) {
        int row = wc * 64 + n * 16 + r16;
        unsigned off = ((unsigned)(row * 128 + (kc * 32 + g4 * 8) * 2)) ^ ((row & 7) << 4);
        bfr[n] = *(bf16x8*)((char*)Bs + off);
      }
#pragma unroll
      for (int m = 0; m < 4; ++m)
#pragma unroll
        for (int n = 0; n < 4; ++n)
          acc[m][n] = __builtin_amdgcn_mfma_f32_16x16x32_bf16(af[m], bfr[n], acc[m][n], 0, 0, 0);
    }
  }

#pragma unroll
  for (int n = 0; n < 4; ++n) {
    int col = col0 + wc * 64 + n * 16 + r16;
    float bv = bias[col];
#pragma unroll
    for (int m = 0; m < 4; ++m) {
      int rbase = row0 + wr * 64 + m * 16 + g4 * 4;
#pragma unroll
      for (int j = 0; j < 4; ++j)
        C[(size_t)(rbase + j) * MODEL_ + col] = acc[m][n][j] + bv;
    }
  }
}

extern "C" void kernel_launch(void* const* d_in, const int* in_sizes, int n_in,
                              void* d_out, int out_size, void* d_ws, size_t ws_size,
                              hipStream_t stream) {
  const float* q = (const float*)d_in[0];
  const float* k = (const float*)d_in[1];
  const float* v = (const float*)d_in[2];
  // d_in[3] = mask: faithfully unused (reference never applies it)
  const float* w_out = (const float*)d_in[4];
  const float* b_out = (const float*)d_in[5];
  float* out = (float*)d_out;

  // ws layout: [attn_bf 16.78MB][X region 33.55MB]
  //   X holds k_bf(4MB)+vt_bf(4MB) during attention, then w_bf (cvt AFTER attn).
  unsigned short* attn_bf = (unsigned short*)d_ws;
  unsigned short* xreg = attn_bf + (size_t)S_ * MODEL_;
  unsigned short* k_bf = xreg;
  unsigned short* vt_bf = xreg + (size_t)G_ * S_ * D_;
  unsigned short* w_bf = xreg;
  if (ws_size < ((size_t)S_ * MODEL_ + (size_t)MODEL_ * MODEL_) * 2) return;

  cvt_k_kernel<<<S_ * G_ * D_ / 4 / 256, 256, 0, stream>>>(k, k_bf);
  dim3 vg(S_ / 64, D_ / 32, G_);
  cvt_v_kernel<<<vg, 256, 0, stream>>>(v, vt_bf);

  dim3 ag(S_ / QB2, H_);
  attn16_kernel<<<ag, 512, 0, stream>>>(q, k_bf, vt_bf, attn_bf);

  cvt_f32_to_bf16<<<(MODEL_ * MODEL_ / 4) / 256, 256, 0, stream>>>(
      w_out, w_bf, MODEL_ * MODEL_ / 4);

  gemm_bt_bias<<<512, 256, 0, stream>>>(attn_bf, w_bf, b_out, out);
}